// Round 2
// baseline (285.291 us; speedup 1.0000x reference)
//
#include <hip/hip_runtime.h>
#include <cstdint>
#include <cstddef>

typedef unsigned short u16;
typedef __bf16 bf16x8 __attribute__((ext_vector_type(8)));
typedef __bf16 bf16x4 __attribute__((ext_vector_type(4)));
typedef float f32x4 __attribute__((ext_vector_type(4)));

#define DEV __device__ __forceinline__

DEV float bf2f(u16 v) { union { unsigned u; float f; } x; x.u = ((unsigned)v) << 16; return x.f; }
DEV u16 f2bf(float f) {
  union { float f; unsigned u; } x; x.f = f;
  unsigned u = x.u + 0x7fffu + ((x.u >> 16) & 1u);
  return (u16)(u >> 16);
}

DEV float fexp2(float x) {
#if __has_builtin(__builtin_amdgcn_exp2f)
  return __builtin_amdgcn_exp2f(x);
#else
  return exp2f(x);
#endif
}

DEV f32x4 mfma16(bf16x8 a, bf16x8 b, f32x4 c) {
  return __builtin_amdgcn_mfma_f32_16x16x32_bf16(a, b, c, 0, 0, 0);
}

DEV void stage16(const void* g, void* l) {
#if __has_builtin(__builtin_amdgcn_global_load_lds)
  __builtin_amdgcn_global_load_lds((__attribute__((address_space(1))) void*)g,
                                   (__attribute__((address_space(3))) void*)l, 16, 0, 0);
#else
  *(uint4*)l = *(const uint4*)g;
#endif
}

// ---------------- fp32 -> bf16 convert ----------------
__global__ __launch_bounds__(256) void cvt_kernel(const float* __restrict__ src,
                                                  u16* __restrict__ dst, int n) {
  int i = (blockIdx.x * 256 + threadIdx.x) * 4;
  if (i >= n) return;
  float4 v = *(const float4*)(src + i);
  ushort4 o;
  o.x = f2bf(v.x); o.y = f2bf(v.y); o.z = f2bf(v.z); o.w = f2bf(v.w);
  *(ushort4*)(dst + i) = o;
}

// ---------------- NT GEMM: C[M][N] = A[M][K] @ B[N][K]^T ----------------
// 128x128 tile, BK=64, 256 threads (4 waves, 2x2), mfma_f32_16x16x32_bf16.
template<int EPI>  // 0: bf16 store to Cb ; 1: fp32 + bias store to Cf
__global__ __launch_bounds__(256) void gemm_nt(const u16* __restrict__ A, const u16* __restrict__ Bm,
                                               int M, int N, int K,
                                               u16* __restrict__ Cb, float* __restrict__ Cf,
                                               const float* __restrict__ bias) {
  __shared__ u16 As[128 * 64];
  __shared__ u16 Bs[128 * 64];
  const int tid = threadIdx.x;
  const int lane = tid & 63;
  const int lo = lane & 15, hi = lane >> 4;
  const int wid = tid >> 6;
  const int wr = wid >> 1, wc = wid & 1;
  const long m0 = (long)blockIdx.y * 128;
  const long n0 = (long)blockIdx.x * 128;

  f32x4 acc[4][4];
  const f32x4 vzero = {0.f, 0.f, 0.f, 0.f};
#pragma unroll
  for (int i = 0; i < 4; ++i)
#pragma unroll
    for (int j = 0; j < 4; ++j) acc[i][j] = vzero;

  const char* Abase = (const char*)(A + m0 * K);
  const char* Bbase = (const char*)(Bm + n0 * K);
  const int Kb = K * 2;
  const int nkt = K >> 6;

  for (int kt = 0; kt < nkt; ++kt) {
    __syncthreads();
    const int kb0 = kt * 128;  // byte offset of this K-slab in a row
#pragma unroll
    for (int i = 0; i < 4; ++i) {
      int o = (i * 256 + tid) * 16;
      int row = o >> 7, kb = o & 127;
      stage16(Abase + (long)row * Kb + kb0 + kb, (char*)As + o);
    }
#pragma unroll
    for (int i = 0; i < 4; ++i) {
      int o = (i * 256 + tid) * 16;
      int row = o >> 7, kb = o & 127;
      stage16(Bbase + (long)row * Kb + kb0 + kb, (char*)Bs + o);
    }
    __syncthreads();
#pragma unroll
    for (int ks = 0; ks < 2; ++ks) {
      bf16x8 af[4], bfr[4];
#pragma unroll
      for (int mi = 0; mi < 4; ++mi)
        af[mi] = *(const bf16x8*)&As[(wr * 64 + mi * 16 + lo) * 64 + ks * 32 + hi * 8];
#pragma unroll
      for (int ni = 0; ni < 4; ++ni)
        bfr[ni] = *(const bf16x8*)&Bs[(wc * 64 + ni * 16 + lo) * 64 + ks * 32 + hi * 8];
#pragma unroll
      for (int mi = 0; mi < 4; ++mi)
#pragma unroll
        for (int ni = 0; ni < 4; ++ni)
          acc[mi][ni] = mfma16(af[mi], bfr[ni], acc[mi][ni]);
    }
  }
#pragma unroll
  for (int mi = 0; mi < 4; ++mi) {
#pragma unroll
    for (int ni = 0; ni < 4; ++ni) {
      const long col = n0 + wc * 64 + ni * 16 + lo;
#pragma unroll
      for (int r = 0; r < 4; ++r) {
        const long row = m0 + wr * 64 + mi * 16 + hi * 4 + r;
        if (EPI == 0) {
          Cb[row * N + col] = f2bf(acc[mi][ni][r]);
        } else {
          Cf[row * N + col] = acc[mi][ni][r] + bias[col];
        }
      }
    }
  }
}

// ---------------- RoPE + (for kv) LayerNorm, head-split ----------------
// one wave per (token m, head h); lane = dh index d in [0,64)
// q is pre-scaled by SCALE * log2(e) so attention softmax runs in exp2 domain.
__global__ __launch_bounds__(256) void rope_ln_kernel(const u16* __restrict__ qkv,
                                                      const float* __restrict__ lng,
                                                      const float* __restrict__ lnb,
                                                      u16* __restrict__ q_b,
                                                      u16* __restrict__ k_b,
                                                      u16* __restrict__ vT_b) {
  const int wid = threadIdx.x >> 6, lane = threadIdx.x & 63;
  const int gw = blockIdx.x * 4 + wid;   // 0..65535
  const int m = gw >> 4, h = gw & 15;    // token, head
  const int b = m >> 11, pos = m & 2047;
  const int d = lane;
  const size_t rowoff = (size_t)m * 2048 + h * 64 + d;
  float qv = bf2f(qkv[rowoff]);
  float kv = bf2f(qkv[rowoff + 1024]);
  const int fi = d & 31;
  float ang = (float)pos * exp2f((float)fi * -0.415241011860919f);
  float sn, cs;
  sincosf(ang, &sn, &cs);
  float qp = __shfl_xor(qv, 32);
  float kp = __shfl_xor(kv, 32);
  float sgn = (d < 32) ? -1.f : 1.f;
  // SCALE * log2(e) = 0.125 * 1.44269504
  float q2 = (qv * cs + sgn * qp * sn) * 0.18033688f;
  float k2 = kv * cs + sgn * kp * sn;
  float sum = k2, sq = k2 * k2;
#pragma unroll
  for (int msk = 32; msk; msk >>= 1) {
    sum += __shfl_xor(sum, msk);
    sq += __shfl_xor(sq, msk);
  }
  float mean = sum * (1.f / 64.f);
  float var = sq * (1.f / 64.f) - mean * mean;
  float rstd = rsqrtf(var + 1e-5f);
  float lk = (k2 - mean) * rstd * lng[d] + lnb[d];
  const int bh = b * 16 + h;
  const size_t o = ((size_t)bh * 2048 + pos) * 64 + d;
  q_b[o] = f2bf(q2);
  u16 lkb = f2bf(lk);
  k_b[o] = lkb;
  vT_b[((size_t)bh * 64 + d) * 2048 + pos] = lkb;
}

// ---------------- fused flash attention (lat causal + ctx full) ----------------
// 1024 blocks x 256 thr; each wave owns 16 q rows, KVBLK=64, exp2-domain
// online softmax with defer-max (THR=8), P bounced through XOR-swizzled LDS.
__global__ __launch_bounds__(256) void attn_kernel(const u16* __restrict__ q_b,
                                                   const u16* __restrict__ k_b,
                                                   const u16* __restrict__ vT_b,
                                                   u16* __restrict__ out_all) {
  __shared__ u16 P_lds[4][16 * 64];   // per-wave 2KB, rows XOR-swizzled by (row&7)<<4
  const int wid = threadIdx.x >> 6, lane = threadIdx.x & 63;
  const int lo = lane & 15, hi = lane >> 4;
  // XCD-aware decode: xcd = bid&7 gets bh in {4*xcd .. 4*xcd+3} (2MB K/V per L2)
  const int bid = blockIdx.x;
  const int xcd = bid & 7, sub = bid >> 3;
  const int bh = (xcd << 2) | (sub & 3);
  const int tile = sub >> 2;           // 0..31
  const int b = bh >> 4, h = bh & 15;
  const bool lat = tile >= 24;
  const int q0 = lat ? 1536 + (tile - 24) * 64 + wid * 16 : tile * 64 + wid * 16;
  const int nkt = lat ? ((q0 + 16 + 63) >> 6) : 24;   // ctx: 1536 keys
  const u16* qbase = q_b + ((size_t)bh * 2048 + q0) * 64;
  const u16* kbase = k_b + (size_t)bh * 2048 * 64;
  const u16* vbase = vT_b + (size_t)bh * 64 * 2048;
  char* pbase = (char*)&P_lds[wid][0];
  const int swz = (lo & 7) << 4;

  bf16x8 aq[2];
#pragma unroll
  for (int ks = 0; ks < 2; ++ks)
    aq[ks] = *(const bf16x8*)(qbase + (size_t)lo * 64 + ks * 32 + hi * 8);

  float mreg = -1e30f, lreg = 0.f;
  f32x4 oacc[4];
  const f32x4 vzero = {0.f, 0.f, 0.f, 0.f};
#pragma unroll
  for (int ni = 0; ni < 4; ++ni) oacc[ni] = vzero;

  for (int kt = 0; kt < nkt; ++kt) {
    const int k0 = kt * 64;
    // QK^T (swapped): lane holds S2[q=lo][key = k0 + hf*16 + hi*4 + r] (log2 units)
    f32x4 sc[4];
#pragma unroll
    for (int hf = 0; hf < 4; ++hf) {
      bf16x8 ak0 = *(const bf16x8*)(kbase + (size_t)(k0 + hf * 16 + lo) * 64 + hi * 8);
      bf16x8 ak1 = *(const bf16x8*)(kbase + (size_t)(k0 + hf * 16 + lo) * 64 + 32 + hi * 8);
      f32x4 s = mfma16(ak0, aq[0], vzero);
      sc[hf] = mfma16(ak1, aq[1], s);
    }
    if (lat) {
      const int qg = q0 + lo;
#pragma unroll
      for (int hf = 0; hf < 4; ++hf)
#pragma unroll
        for (int r = 0; r < 4; ++r)
          if (k0 + hf * 16 + hi * 4 + r > qg) sc[hf][r] = -1e30f;
    }
    // row max (per q = lo), reduced across the 4 lanes sharing lo
    float tmax = sc[0][0];
#pragma unroll
    for (int hf = 0; hf < 4; ++hf)
#pragma unroll
      for (int r = 0; r < 4; ++r) tmax = fmaxf(tmax, sc[hf][r]);
    tmax = fmaxf(tmax, __shfl_xor(tmax, 16));
    tmax = fmaxf(tmax, __shfl_xor(tmax, 32));
    // defer-max: rescale only when the running max grew by more than THR=8
    if (__any(tmax > mreg + 8.0f)) {
      float mnew = fmaxf(mreg, tmax);
      float scale = fexp2(mreg - mnew);
      mreg = mnew;
      lreg *= scale;
      float scr[4];
#pragma unroll
      for (int r = 0; r < 4; ++r) scr[r] = __shfl(scale, hi * 4 + r);
#pragma unroll
      for (int ni = 0; ni < 4; ++ni)
#pragma unroll
        for (int r = 0; r < 4; ++r) oacc[ni][r] *= scr[r];
    }
    // P = 2^(S2 - m), pack to bf16, store swizzled
    float psum = 0.f;
#pragma unroll
    for (int hf = 0; hf < 4; ++hf) {
      float p[4];
#pragma unroll
      for (int r = 0; r < 4; ++r) {
        p[r] = fexp2(sc[hf][r] - mreg);
        psum += p[r];
      }
      bf16x4 w = {(__bf16)p[0], (__bf16)p[1], (__bf16)p[2], (__bf16)p[3]};
      *(bf16x4*)(pbase + ((lo * 128 + hf * 32 + hi * 8) ^ swz)) = w;
    }
    psum += __shfl_xor(psum, 16);
    psum += __shfl_xor(psum, 32);
    lreg += psum;
    // PV: A = P[16q x 32k] (swizzled read), B = V^T rows (d-major)
    bf16x8 ap0 = *(const bf16x8*)(pbase + ((lo * 128 + hi * 16) ^ swz));
    bf16x8 ap1 = *(const bf16x8*)(pbase + ((lo * 128 + 64 + hi * 16) ^ swz));
#pragma unroll
    for (int ni = 0; ni < 4; ++ni) {
      bf16x8 bv0 = *(const bf16x8*)(vbase + (size_t)(ni * 16 + lo) * 2048 + k0 + hi * 8);
      bf16x8 bv1 = *(const bf16x8*)(vbase + (size_t)(ni * 16 + lo) * 2048 + k0 + 32 + hi * 8);
      oacc[ni] = mfma16(ap0, bv0, oacc[ni]);
      oacc[ni] = mfma16(ap1, bv1, oacc[ni]);
    }
  }
  // epilogue: O[q = hi*4+r][d = ni*16+lo], normalize by l (held at lane q)
  const int orow0 = lat ? (q0 - 1536) : (512 + q0);
  float ldiv[4];
#pragma unroll
  for (int r = 0; r < 4; ++r) ldiv[r] = 1.f / __shfl(lreg, hi * 4 + r);
#pragma unroll
  for (int ni = 0; ni < 4; ++ni)
#pragma unroll
    for (int r = 0; r < 4; ++r) {
      const int orow = orow0 + hi * 4 + r;
      out_all[((size_t)b * 2048 + orow) * 1024 + h * 64 + ni * 16 + lo] =
          f2bf(oacc[ni][r] * ldiv[r]);
    }
}

extern "C" void kernel_launch(void* const* d_in, const int* in_sizes, int n_in,
                              void* d_out, int out_size, void* d_ws, size_t ws_size,
                              hipStream_t stream) {
  const float* x    = (const float*)d_in[0];
  const float* Wq   = (const float*)d_in[1];
  const float* Wkv  = (const float*)d_in[2];
  const float* Wo   = (const float*)d_in[3];
  const float* bo   = (const float*)d_in[4];
  const float* ln_g = (const float*)d_in[5];
  const float* ln_b = (const float*)d_in[6];
  float* out = (float*)d_out;
  char* ws = (char*)d_ws;

  u16* xb      = (u16*)(ws + 0);                      // [4096][1024] 8MB (dead after gemm1)
  u16* out_all = (u16*)(ws + 0);                      // [4096][1024] 8MB
  u16* wqkv_b  = (u16*)(ws + (size_t)(8u << 20));     // [2048][1024] 4MB
  u16* wo_b    = (u16*)(ws + (size_t)(12u << 20));    // [1024][1024] 2MB
  u16* qkv_b   = (u16*)(ws + (size_t)(14u << 20));    // [4096][2048] 16MB
  u16* q_b     = (u16*)(ws + (size_t)(30u << 20));    // [32][2048][64] 8MB
  u16* k_b     = (u16*)(ws + (size_t)(38u << 20));    // [32][2048][64] 8MB
  u16* vT_b    = (u16*)(ws + (size_t)(46u << 20));    // [32][64][2048] 8MB

  cvt_kernel<<<4096, 256, 0, stream>>>(x, xb, 4194304);
  cvt_kernel<<<1024, 256, 0, stream>>>(Wq, wqkv_b, 1048576);
  cvt_kernel<<<1024, 256, 0, stream>>>(Wkv, wqkv_b + 1048576, 1048576);
  cvt_kernel<<<1024, 256, 0, stream>>>(Wo, wo_b, 1048576);

  gemm_nt<0><<<dim3(16, 32), 256, 0, stream>>>(xb, wqkv_b, 4096, 2048, 1024,
                                               qkv_b, nullptr, nullptr);
  rope_ln_kernel<<<16384, 256, 0, stream>>>(qkv_b, ln_g, ln_b, q_b, k_b, vT_b);
  attn_kernel<<<1024, 256, 0, stream>>>(q_b, k_b, vT_b, out_all);
  gemm_nt<1><<<dim3(8, 32), 256, 0, stream>>>(out_all, wo_b, 4096, 1024, 1024,
                                              nullptr, out, bo);
}

// Round 3
// 159.111 us; speedup vs baseline: 1.7930x; 1.7930x over previous
//
#include <hip/hip_runtime.h>
#include <cstdint>
#include <cstddef>

typedef unsigned short u16;
typedef __bf16 bf16x8 __attribute__((ext_vector_type(8)));
typedef __bf16 bf16x4 __attribute__((ext_vector_type(4)));
typedef float f32x4 __attribute__((ext_vector_type(4)));

#define DEV __device__ __forceinline__

DEV float bf2f(u16 v) { union { unsigned u; float f; } x; x.u = ((unsigned)v) << 16; return x.f; }
DEV u16 f2bf(float f) {
  union { float f; unsigned u; } x; x.f = f;
  unsigned u = x.u + 0x7fffu + ((x.u >> 16) & 1u);
  return (u16)(u >> 16);
}

DEV float fexp2(float x) {
#if __has_builtin(__builtin_amdgcn_exp2f)
  return __builtin_amdgcn_exp2f(x);
#else
  return exp2f(x);
#endif
}

DEV f32x4 mfma16(bf16x8 a, bf16x8 b, f32x4 c) {
  return __builtin_amdgcn_mfma_f32_16x16x32_bf16(a, b, c, 0, 0, 0);
}

DEV void stage16(const void* g, void* l) {
#if __has_builtin(__builtin_amdgcn_global_load_lds)
  __builtin_amdgcn_global_load_lds((__attribute__((address_space(1))) void*)g,
                                   (__attribute__((address_space(3))) void*)l, 16, 0, 0);
#else
  *(uint4*)l = *(const uint4*)g;
#endif
}

// ---------------- fp32 -> bf16 convert ----------------
__global__ __launch_bounds__(256) void cvt_kernel(const float* __restrict__ src,
                                                  u16* __restrict__ dst, int n) {
  int i = (blockIdx.x * 256 + threadIdx.x) * 4;
  if (i >= n) return;
  float4 v = *(const float4*)(src + i);
  ushort4 o;
  o.x = f2bf(v.x); o.y = f2bf(v.y); o.z = f2bf(v.z); o.w = f2bf(v.w);
  *(ushort4*)(dst + i) = o;
}

// ---------------- NT GEMM: C[M][N] = A[M][K] @ B[N][K]^T ----------------
template<int EPI>
__global__ __launch_bounds__(256) void gemm_nt(const u16* __restrict__ A, const u16* __restrict__ Bm,
                                               int M, int N, int K,
                                               u16* __restrict__ Cb, float* __restrict__ Cf,
                                               const float* __restrict__ bias) {
  __shared__ u16 As[128 * 64];
  __shared__ u16 Bs[128 * 64];
  const int tid = threadIdx.x;
  const int lane = tid & 63;
  const int lo = lane & 15, hi = lane >> 4;
  const int wid = tid >> 6;
  const int wr = wid >> 1, wc = wid & 1;
  const long m0 = (long)blockIdx.y * 128;
  const long n0 = (long)blockIdx.x * 128;

  f32x4 acc[4][4];
  const f32x4 vzero = {0.f, 0.f, 0.f, 0.f};
#pragma unroll
  for (int i = 0; i < 4; ++i)
#pragma unroll
    for (int j = 0; j < 4; ++j) acc[i][j] = vzero;

  const char* Abase = (const char*)(A + m0 * K);
  const char* Bbase = (const char*)(Bm + n0 * K);
  const int Kb = K * 2;
  const int nkt = K >> 6;

  for (int kt = 0; kt < nkt; ++kt) {
    __syncthreads();
    const int kb0 = kt * 128;
#pragma unroll
    for (int i = 0; i < 4; ++i) {
      int o = (i * 256 + tid) * 16;
      int row = o >> 7, kb = o & 127;
      stage16(Abase + (long)row * Kb + kb0 + kb, (char*)As + o);
    }
#pragma unroll
    for (int i = 0; i < 4; ++i) {
      int o = (i * 256 + tid) * 16;
      int row = o >> 7, kb = o & 127;
      stage16(Bbase + (long)row * Kb + kb0 + kb, (char*)Bs + o);
    }
    __syncthreads();
#pragma unroll
    for (int ks = 0; ks < 2; ++ks) {
      bf16x8 af[4], bfr[4];
#pragma unroll
      for (int mi = 0; mi < 4; ++mi)
        af[mi] = *(const bf16x8*)&As[(wr * 64 + mi * 16 + lo) * 64 + ks * 32 + hi * 8];
#pragma unroll
      for (int ni = 0; ni < 4; ++ni)
        bfr[ni] = *(const bf16x8*)&Bs[(wc * 64 + ni * 16 + lo) * 64 + ks * 32 + hi * 8];
#pragma unroll
      for (int mi = 0; mi < 4; ++mi)
#pragma unroll
        for (int ni = 0; ni < 4; ++ni)
          acc[mi][ni] = mfma16(af[mi], bfr[ni], acc[mi][ni]);
    }
  }
#pragma unroll
  for (int mi = 0; mi < 4; ++mi) {
#pragma unroll
    for (int ni = 0; ni < 4; ++ni) {
      const long col = n0 + wc * 64 + ni * 16 + lo;
#pragma unroll
      for (int r = 0; r < 4; ++r) {
        const long row = m0 + wr * 64 + mi * 16 + hi * 4 + r;
        if (EPI == 0) {
          Cb[row * N + col] = f2bf(acc[mi][ni][r]);
        } else {
          Cf[row * N + col] = acc[mi][ni][r] + bias[col];
        }
      }
    }
  }
}

// ---------------- RoPE + LayerNorm ----------------
__global__ __launch_bounds__(256) void rope_ln_kernel(const u16* __restrict__ qkv,
                                                      const float* __restrict__ lng,
                                                      const float* __restrict__ lnb,
                                                      u16* __restrict__ q_b,
                                                      u16* __restrict__ k_b,
                                                      u16* __restrict__ vT_b) {
  const int wid = threadIdx.x >> 6, lane = threadIdx.x & 63;
  const int gw = blockIdx.x * 4 + wid;
  const int m = gw >> 4, h = gw & 15;
  const int b = m >> 11, pos = m & 2047;
  const int d = lane;
  const size_t rowoff = (size_t)m * 2048 + h * 64 + d;
  float qv = bf2f(qkv[rowoff]);
  float kv = bf2f(qkv[rowoff + 1024]);
  const int fi = d & 31;
  float ang = (float)pos * exp2f((float)fi * -0.415241011860919f);
  float sn, cs;
  sincosf(ang, &sn, &cs);
  float qp = __shfl_xor(qv, 32);
  float kp = __shfl_xor(kv, 32);
  float sgn = (d < 32) ? -1.f : 1.f;
  float q2 = (qv * cs + sgn * qp * sn) * 0.18033688f;  // SCALE*log2(e)
  float k2 = kv * cs + sgn * kp * sn;
  float sum = k2, sq = k2 * k2;
#pragma unroll
  for (int msk = 32; msk; msk >>= 1) {
    sum += __shfl_xor(sum, msk);
    sq += __shfl_xor(sq, msk);
  }
  float mean = sum * (1.f / 64.f);
  float var = sq * (1.f / 64.f) - mean * mean;
  float rstd = rsqrtf(var + 1e-5f);
  float lk = (k2 - mean) * rstd * lng[d] + lnb[d];
  const int bh = b * 16 + h;
  const size_t o = ((size_t)bh * 2048 + pos) * 64 + d;
  q_b[o] = f2bf(q2);
  u16 lkb = f2bf(lk);
  k_b[o] = lkb;
  vT_b[((size_t)bh * 64 + d) * 2048 + pos] = lkb;
}

// ---------------- fused flash attention ----------------
// 256 blocks x 512 thr (8 waves). Block = 256 q rows of one bh; wave = 32 q rows
// (2 s-blocks of 16). K/V double-buffered in LDS via swizzled-source
// global_load_lds; reads XOR-swizzled (conflict-free). exp2-domain softmax,
// defer-max (init m=8, THR=8), per-lane l accumulation.
__global__ __launch_bounds__(512) void attn_kernel(const u16* __restrict__ q_b,
                                                   const u16* __restrict__ k_b,
                                                   const u16* __restrict__ vT_b,
                                                   u16* __restrict__ out_all) {
  __shared__ u16 Ks[2][4096];       // [buf][64 keys][64 d]  rows 128B
  __shared__ u16 Vs[2][4096];       // [buf][64 d][64 keys]  rows 128B
  __shared__ u16 P_lds[8][2][1024]; // [wave][s][16 q][64 k]
  const int tid = threadIdx.x;
  const int wid = tid >> 6, lane = tid & 63;
  const int lo = lane & 15, hi = lane >> 4;
  const int bid = blockIdx.x;
  const int xcd = bid & 7, rest = bid >> 3;
  const int bh = (xcd << 2) | (rest & 3);
  const int tb = rest >> 2;                  // 0..7
  const int b = bh >> 4, h = bh & 15;
  const bool lat = tb >= 6;
  const int q0b = lat ? 1536 + (tb - 6) * 256 : tb * 256;
  const int q0w = q0b + wid * 32;
  const int nkt = lat ? ((q0b + 256) >> 6) : 24;
  const int wave_kmax = lat ? (q0w + 31) : 1535;
  const u16* qbase = q_b + ((size_t)bh * 2048 + q0w) * 64;
  const char* kg = (const char*)(k_b + (size_t)bh * 2048 * 64);
  const char* vg = (const char*)(vT_b + (size_t)bh * 64 * 2048);
  const f32x4 vzero = {0.f, 0.f, 0.f, 0.f};

  bf16x8 aq[2][2];
#pragma unroll
  for (int s = 0; s < 2; ++s)
#pragma unroll
    for (int ks = 0; ks < 2; ++ks)
      aq[s][ks] = *(const bf16x8*)(qbase + (size_t)(s * 16 + lo) * 64 + ks * 32 + hi * 8);

  float mreg[2] = {8.f, 8.f};
  float lsum[2] = {0.f, 0.f};
  f32x4 oacc[2][4];
#pragma unroll
  for (int s = 0; s < 2; ++s)
#pragma unroll
    for (int ni = 0; ni < 4; ++ni) oacc[s][ni] = vzero;

  // staging geometry: 512 thr x 16B = one 8KB tile per buffer
  const int so = tid * 16;
  const int srow = so >> 7;
  const int scb = (so & 127) ^ ((srow & 7) << 4);  // pre-swizzled source column

  // prologue: stage tile 0
  stage16(kg + (size_t)srow * 128 + scb, (char*)Ks[0] + so);
  stage16(vg + (size_t)srow * 4096 + scb, (char*)Vs[0] + so);
  __syncthreads();

  int cur = 0;
  for (int kt = 0; kt < nkt; ++kt) {
    const int k0 = kt << 6;
    if (kt + 1 < nkt) {  // stage next tile into the other buffer (overlaps compute)
      const int k0n = k0 + 64;
      stage16(kg + (size_t)(k0n + srow) * 128 + scb, (char*)Ks[cur ^ 1] + so);
      stage16(vg + (size_t)srow * 4096 + (size_t)(k0n << 1) + scb, (char*)Vs[cur ^ 1] + so);
    }
    if (k0 <= wave_kmax) {
      // K fragments from swizzled LDS
      bf16x8 kf[4][2];
#pragma unroll
      for (int hf = 0; hf < 4; ++hf) {
        const int row = hf * 16 + lo;
        const char* rb = (const char*)Ks[cur] + row * 128;
        const int sw = (row & 7) << 4;
        kf[hf][0] = *(const bf16x8*)(rb + ((hi * 16) ^ sw));
        kf[hf][1] = *(const bf16x8*)(rb + ((64 + hi * 16) ^ sw));
      }
      f32x4 sc[2][4];
      __builtin_amdgcn_s_setprio(1);
#pragma unroll
      for (int s = 0; s < 2; ++s)
#pragma unroll
        for (int hf = 0; hf < 4; ++hf) {
          f32x4 t = mfma16(kf[hf][0], aq[s][0], vzero);
          sc[s][hf] = mfma16(kf[hf][1], aq[s][1], t);
        }
      __builtin_amdgcn_s_setprio(0);

      const bool straddle = lat && (k0 + 63 > q0w);
#pragma unroll
      for (int s = 0; s < 2; ++s) {
        if (straddle) {
          const int qg = q0w + s * 16 + lo;
#pragma unroll
          for (int hf = 0; hf < 4; ++hf)
#pragma unroll
            for (int r = 0; r < 4; ++r)
              if (k0 + hf * 16 + hi * 4 + r > qg) sc[s][hf][r] = -1e30f;
        }
        float tmax = sc[s][0][0];
#pragma unroll
        for (int hf = 0; hf < 4; ++hf)
#pragma unroll
          for (int r = 0; r < 4; ++r) tmax = fmaxf(tmax, sc[s][hf][r]);
        tmax = fmaxf(tmax, __shfl_xor(tmax, 16));
        tmax = fmaxf(tmax, __shfl_xor(tmax, 32));
        if (__any(tmax > mreg[s] + 8.0f)) {  // defer-max (rare)
          float mnew = fmaxf(mreg[s], tmax);
          float scale = fexp2(mreg[s] - mnew);
          mreg[s] = mnew;
          lsum[s] *= scale;
          float scr[4];
#pragma unroll
          for (int r = 0; r < 4; ++r) scr[r] = __shfl(scale, hi * 4 + r);
#pragma unroll
          for (int ni = 0; ni < 4; ++ni)
#pragma unroll
            for (int r = 0; r < 4; ++r) oacc[s][ni][r] *= scr[r];
        }
        char* pb = (char*)&P_lds[wid][s][0] + lo * 128;
        const int psw = (lo & 7) << 4;
        float ps = 0.f;
#pragma unroll
        for (int hf = 0; hf < 4; ++hf) {
          float p[4];
#pragma unroll
          for (int r = 0; r < 4; ++r) {
            p[r] = fexp2(sc[s][hf][r] - mreg[s]);
            ps += p[r];
          }
          bf16x4 w = {(__bf16)p[0], (__bf16)p[1], (__bf16)p[2], (__bf16)p[3]};
          *(bf16x4*)(pb + ((hf * 32 + hi * 8) ^ psw)) = w;
        }
        lsum[s] += ps;  // per-lane partial; reduced once at the end
      }
      // PV
      bf16x8 ap[2][2], bv[4][2];
      {
        const int psw = (lo & 7) << 4;
#pragma unroll
        for (int s = 0; s < 2; ++s) {
          const char* pb = (const char*)&P_lds[wid][s][0] + lo * 128;
          ap[s][0] = *(const bf16x8*)(pb + ((hi * 16) ^ psw));
          ap[s][1] = *(const bf16x8*)(pb + ((64 + hi * 16) ^ psw));
        }
      }
#pragma unroll
      for (int ni = 0; ni < 4; ++ni) {
        const int row = ni * 16 + lo;
        const char* rb = (const char*)Vs[cur] + row * 128;
        const int sw = (row & 7) << 4;
        bv[ni][0] = *(const bf16x8*)(rb + ((hi * 16) ^ sw));
        bv[ni][1] = *(const bf16x8*)(rb + ((64 + hi * 16) ^ sw));
      }
      __builtin_amdgcn_s_setprio(1);
#pragma unroll
      for (int s = 0; s < 2; ++s)
#pragma unroll
        for (int ni = 0; ni < 4; ++ni) {
          f32x4 t = mfma16(ap[s][0], bv[ni][0], oacc[s][ni]);
          oacc[s][ni] = mfma16(ap[s][1], bv[ni][1], t);
        }
      __builtin_amdgcn_s_setprio(0);
    }
    __syncthreads();
    cur ^= 1;
  }
  // epilogue: O[q = s*16+hi*4+r][d = ni*16+lo]
  const int orow0 = lat ? (q0w - 1536) : (512 + q0w);
#pragma unroll
  for (int s = 0; s < 2; ++s) {
    lsum[s] += __shfl_xor(lsum[s], 16);
    lsum[s] += __shfl_xor(lsum[s], 32);
    float ldiv[4];
#pragma unroll
    for (int r = 0; r < 4; ++r) ldiv[r] = 1.f / __shfl(lsum[s], hi * 4 + r);
#pragma unroll
    for (int ni = 0; ni < 4; ++ni)
#pragma unroll
      for (int r = 0; r < 4; ++r) {
        const int orow = orow0 + s * 16 + hi * 4 + r;
        out_all[((size_t)b * 2048 + orow) * 1024 + h * 64 + ni * 16 + lo] =
            f2bf(oacc[s][ni][r] * ldiv[r]);
      }
  }
}

extern "C" void kernel_launch(void* const* d_in, const int* in_sizes, int n_in,
                              void* d_out, int out_size, void* d_ws, size_t ws_size,
                              hipStream_t stream) {
  const float* x    = (const float*)d_in[0];
  const float* Wq   = (const float*)d_in[1];
  const float* Wkv  = (const float*)d_in[2];
  const float* Wo   = (const float*)d_in[3];
  const float* bo   = (const float*)d_in[4];
  const float* ln_g = (const float*)d_in[5];
  const float* ln_b = (const float*)d_in[6];
  float* out = (float*)d_out;
  char* ws = (char*)d_ws;

  u16* xb      = (u16*)(ws + 0);                      // 8MB (dead after gemm1)
  u16* out_all = (u16*)(ws + 0);                      // 8MB
  u16* wqkv_b  = (u16*)(ws + (size_t)(8u << 20));     // 4MB
  u16* wo_b    = (u16*)(ws + (size_t)(12u << 20));    // 2MB
  u16* qkv_b   = (u16*)(ws + (size_t)(14u << 20));    // 16MB
  u16* q_b     = (u16*)(ws + (size_t)(30u << 20));    // 8MB
  u16* k_b     = (u16*)(ws + (size_t)(38u << 20));    // 8MB
  u16* vT_b    = (u16*)(ws + (size_t)(46u << 20));    // 8MB

  cvt_kernel<<<4096, 256, 0, stream>>>(x, xb, 4194304);
  cvt_kernel<<<1024, 256, 0, stream>>>(Wq, wqkv_b, 1048576);
  cvt_kernel<<<1024, 256, 0, stream>>>(Wkv, wqkv_b + 1048576, 1048576);
  cvt_kernel<<<1024, 256, 0, stream>>>(Wo, wo_b, 1048576);

  gemm_nt<0><<<dim3(16, 32), 256, 0, stream>>>(xb, wqkv_b, 4096, 2048, 1024,
                                               qkv_b, nullptr, nullptr);
  rope_ln_kernel<<<16384, 256, 0, stream>>>(qkv_b, ln_g, ln_b, q_b, k_b, vT_b);
  attn_kernel<<<256, 512, 0, stream>>>(q_b, k_b, vT_b, out_all);
  gemm_nt<1><<<dim3(8, 32), 256, 0, stream>>>(out_all, wo_b, 4096, 1024, 1024,
                                              nullptr, out, bo);
}

// Round 4
// 143.539 us; speedup vs baseline: 1.9875x; 1.1085x over previous
//
#include <hip/hip_runtime.h>
#include <cstdint>
#include <cstddef>

typedef unsigned short u16;
typedef __bf16 bf16x8 __attribute__((ext_vector_type(8)));
typedef __bf16 bf16x2 __attribute__((ext_vector_type(2)));
typedef float f32x4 __attribute__((ext_vector_type(4)));
typedef float f32x16 __attribute__((ext_vector_type(16)));

#define DEV __device__ __forceinline__

DEV float bf2f(u16 v) { union { unsigned u; float f; } x; x.u = ((unsigned)v) << 16; return x.f; }
DEV u16 f2bf(float f) {
  union { float f; unsigned u; } x; x.f = f;
  unsigned u = x.u + 0x7fffu + ((x.u >> 16) & 1u);
  return (u16)(u >> 16);
}

DEV float fexp2(float x) {
#if __has_builtin(__builtin_amdgcn_exp2f)
  return __builtin_amdgcn_exp2f(x);
#else
  return exp2f(x);
#endif
}

DEV f32x4 mfma16(bf16x8 a, bf16x8 b, f32x4 c) {
  return __builtin_amdgcn_mfma_f32_16x16x32_bf16(a, b, c, 0, 0, 0);
}
DEV f32x16 mfma32(bf16x8 a, bf16x8 b, f32x16 c) {
  return __builtin_amdgcn_mfma_f32_32x32x16_bf16(a, b, c, 0, 0, 0);
}

DEV void stage16(const void* g, void* l) {
#if __has_builtin(__builtin_amdgcn_global_load_lds)
  __builtin_amdgcn_global_load_lds((__attribute__((address_space(1))) void*)g,
                                   (__attribute__((address_space(3))) void*)l, 16, 0, 0);
#else
  *(uint4*)l = *(const uint4*)g;
#endif
}

// pack two floats to one u32 of 2 bf16 (compiler emits v_cvt_pk_bf16_f32)
DEV unsigned pkbf(float a, float b) {
  bf16x2 v = {(__bf16)a, (__bf16)b};
  return __builtin_bit_cast(unsigned, v);
}

// v_permlane32_swap_b32: swap lanes 32-63 of a with lanes 0-31 of b.
// post: a = {a.lo, b.lo}, b = {a.hi, b.hi}  (lane-index-preserving within halves)
DEV void plswap(unsigned& a, unsigned& b) {
#if __has_builtin(__builtin_amdgcn_permlane32_swap)
  auto r = __builtin_amdgcn_permlane32_swap(a, b, false, false);
  a = (unsigned)r[0];
  b = (unsigned)r[1];
#else
  unsigned sa = __shfl_xor((int)a, 32), sb = __shfl_xor((int)b, 32);
  bool hi = ((threadIdx.x & 63) >> 5) != 0;
  unsigned na = hi ? sb : a;
  unsigned nb = hi ? b : sa;
  a = na; b = nb;
#endif
}

// ---------------- fp32 -> bf16 convert ----------------
__global__ __launch_bounds__(256) void cvt_kernel(const float* __restrict__ src,
                                                  u16* __restrict__ dst, int n) {
  int i = (blockIdx.x * 256 + threadIdx.x) * 4;
  if (i >= n) return;
  float4 v = *(const float4*)(src + i);
  ushort4 o;
  o.x = f2bf(v.x); o.y = f2bf(v.y); o.z = f2bf(v.z); o.w = f2bf(v.w);
  *(ushort4*)(dst + i) = o;
}

// all three weight matrices in one launch (1024 blocks each)
__global__ __launch_bounds__(256) void cvtW_kernel(const float* __restrict__ Wq,
                                                   const float* __restrict__ Wkv,
                                                   const float* __restrict__ Wo,
                                                   u16* __restrict__ wqkv,
                                                   u16* __restrict__ wo) {
  const int seg = blockIdx.x >> 10;
  const int i = ((blockIdx.x & 1023) * 256 + threadIdx.x) * 4;
  const float* src = seg == 0 ? Wq : (seg == 1 ? Wkv : Wo);
  u16* dst = seg == 0 ? wqkv : (seg == 1 ? wqkv + 1048576 : wo);
  float4 v = *(const float4*)(src + i);
  ushort4 o;
  o.x = f2bf(v.x); o.y = f2bf(v.y); o.z = f2bf(v.z); o.w = f2bf(v.w);
  *(ushort4*)(dst + i) = o;
}

// ---------------- NT GEMM: C[M][N] = A[M][K] @ B[N][K]^T ----------------
template<int EPI>
__global__ __launch_bounds__(256) void gemm_nt(const u16* __restrict__ A, const u16* __restrict__ Bm,
                                               int M, int N, int K,
                                               u16* __restrict__ Cb, float* __restrict__ Cf,
                                               const float* __restrict__ bias) {
  __shared__ u16 As[128 * 64];
  __shared__ u16 Bs[128 * 64];
  const int tid = threadIdx.x;
  const int lane = tid & 63;
  const int lo = lane & 15, hi = lane >> 4;
  const int wid = tid >> 6;
  const int wr = wid >> 1, wc = wid & 1;
  const long m0 = (long)blockIdx.y * 128;
  const long n0 = (long)blockIdx.x * 128;

  f32x4 acc[4][4];
  const f32x4 vzero = {0.f, 0.f, 0.f, 0.f};
#pragma unroll
  for (int i = 0; i < 4; ++i)
#pragma unroll
    for (int j = 0; j < 4; ++j) acc[i][j] = vzero;

  const char* Abase = (const char*)(A + m0 * K);
  const char* Bbase = (const char*)(Bm + n0 * K);
  const int Kb = K * 2;
  const int nkt = K >> 6;

  for (int kt = 0; kt < nkt; ++kt) {
    __syncthreads();
    const int kb0 = kt * 128;
#pragma unroll
    for (int i = 0; i < 4; ++i) {
      int o = (i * 256 + tid) * 16;
      int row = o >> 7, kb = o & 127;
      stage16(Abase + (long)row * Kb + kb0 + kb, (char*)As + o);
    }
#pragma unroll
    for (int i = 0; i < 4; ++i) {
      int o = (i * 256 + tid) * 16;
      int row = o >> 7, kb = o & 127;
      stage16(Bbase + (long)row * Kb + kb0 + kb, (char*)Bs + o);
    }
    __syncthreads();
#pragma unroll
    for (int ks = 0; ks < 2; ++ks) {
      bf16x8 af[4], bfr[4];
#pragma unroll
      for (int mi = 0; mi < 4; ++mi)
        af[mi] = *(const bf16x8*)&As[(wr * 64 + mi * 16 + lo) * 64 + ks * 32 + hi * 8];
#pragma unroll
      for (int ni = 0; ni < 4; ++ni)
        bfr[ni] = *(const bf16x8*)&Bs[(wc * 64 + ni * 16 + lo) * 64 + ks * 32 + hi * 8];
#pragma unroll
      for (int mi = 0; mi < 4; ++mi)
#pragma unroll
        for (int ni = 0; ni < 4; ++ni)
          acc[mi][ni] = mfma16(af[mi], bfr[ni], acc[mi][ni]);
    }
  }
#pragma unroll
  for (int mi = 0; mi < 4; ++mi) {
#pragma unroll
    for (int ni = 0; ni < 4; ++ni) {
      const long col = n0 + wc * 64 + ni * 16 + lo;
#pragma unroll
      for (int r = 0; r < 4; ++r) {
        const long row = m0 + wr * 64 + mi * 16 + hi * 4 + r;
        if (EPI == 0) {
          Cb[row * N + col] = f2bf(acc[mi][ni][r]);
        } else {
          Cf[row * N + col] = acc[mi][ni][r] + bias[col];
        }
      }
    }
  }
}

// ---------------- RoPE + LayerNorm ----------------
__global__ __launch_bounds__(256) void rope_ln_kernel(const u16* __restrict__ qkv,
                                                      const float* __restrict__ lng,
                                                      const float* __restrict__ lnb,
                                                      u16* __restrict__ q_b,
                                                      u16* __restrict__ k_b,
                                                      u16* __restrict__ vT_b) {
  const int wid = threadIdx.x >> 6, lane = threadIdx.x & 63;
  const int gw = blockIdx.x * 4 + wid;
  const int m = gw >> 4, h = gw & 15;
  const int b = m >> 11, pos = m & 2047;
  const int d = lane;
  const size_t rowoff = (size_t)m * 2048 + h * 64 + d;
  float qv = bf2f(qkv[rowoff]);
  float kv = bf2f(qkv[rowoff + 1024]);
  const int fi = d & 31;
  float ang = (float)pos * exp2f((float)fi * -0.415241011860919f);
  float sn, cs;
  sincosf(ang, &sn, &cs);
  float qp = __shfl_xor(qv, 32);
  float kp = __shfl_xor(kv, 32);
  float sgn = (d < 32) ? -1.f : 1.f;
  float q2 = (qv * cs + sgn * qp * sn) * 0.18033688f;  // SCALE*log2(e)
  float k2 = kv * cs + sgn * kp * sn;
  float sum = k2, sq = k2 * k2;
#pragma unroll
  for (int msk = 32; msk; msk >>= 1) {
    sum += __shfl_xor(sum, msk);
    sq += __shfl_xor(sq, msk);
  }
  float mean = sum * (1.f / 64.f);
  float var = sq * (1.f / 64.f) - mean * mean;
  float rstd = rsqrtf(var + 1e-5f);
  float lk = (k2 - mean) * rstd * lng[d] + lnb[d];
  const int bh = b * 16 + h;
  const size_t o = ((size_t)bh * 2048 + pos) * 64 + d;
  q_b[o] = f2bf(q2);
  u16 lkb = f2bf(lk);
  k_b[o] = lkb;
  vT_b[((size_t)bh * 64 + d) * 2048 + pos] = lkb;
}

// ---------------- fused flash attention (32x32 MFMA, in-register P) ----------
// 512 blocks x 256 thr (4 waves, 2 blocks/CU). Wave = 32 q rows. KVBLK=64.
// Swapped QK (S^T): lane (l31,lh) = col q=l31, rows = keys (r&3)+8(r>>2)+4lh.
// Softmax fully per-lane (one q per lane); P -> PV A-frags via cvt_pk +
// permlane32_swap (no LDS bounce). K/V double-buffered in swizzled LDS.
__global__ __launch_bounds__(256, 2) void attn_kernel(const u16* __restrict__ q_b,
                                                      const u16* __restrict__ k_b,
                                                      const u16* __restrict__ vT_b,
                                                      u16* __restrict__ out_all) {
  __shared__ __align__(16) u16 Ks[2][4096];   // [buf][64 keys][64 d], swizzled
  __shared__ __align__(16) u16 Vs[2][4096];   // [buf][64 d][64 keys], swizzled
  __shared__ float ldsL[4][32];
  const int tid = threadIdx.x;
  const int wid = tid >> 6, lane = tid & 63;
  const int l31 = lane & 31, lh = lane >> 5;
  const int bid = blockIdx.x;
  const int xcd = bid & 7, rest = bid >> 3;   // 512 = 8 xcd * 4 bh * 16 tiles
  const int bh = (xcd << 2) | (rest & 3);
  const int tile = rest >> 2;                 // 0..15
  const int b = bh >> 4, h = bh & 15;
  const bool lat = tile >= 12;
  const int q0b = lat ? 1536 + (tile - 12) * 128 : tile * 128;
  const int q0w = q0b + wid * 32;
  const int nkt = lat ? ((q0b + 128) >> 6) : 24;
  const int wave_kmax = lat ? (q0w + 31) : 1535;
  const char* kg = (const char*)(k_b + (size_t)bh * 2048 * 64);
  const char* vg = (const char*)(vT_b + (size_t)bh * 64 * 2048);
  const f32x16 vzero16 = {0.f,0.f,0.f,0.f,0.f,0.f,0.f,0.f,0.f,0.f,0.f,0.f,0.f,0.f,0.f,0.f};

  // Q B-frags: col=q=l31, k=d = ds*16 + lh*8 + j
  const u16* qrow = q_b + ((size_t)bh * 2048 + q0w + l31) * 64;
  bf16x8 qf[4];
#pragma unroll
  for (int ds = 0; ds < 4; ++ds)
    qf[ds] = *(const bf16x8*)(qrow + ds * 16 + lh * 8);

  float mreg = 8.f, lsum = 0.f;
  f32x16 oacc[2];
  oacc[0] = vzero16; oacc[1] = vzero16;

  // staging: 256 thr x 16B x 2 chunks per operand = 8KB tile
  const int so = tid * 16;

  // prologue: stage tile 0
#pragma unroll
  for (int i = 0; i < 2; ++i) {
    const int off = so + i * 4096;
    const int row = off >> 7, colb = off & 127;
    const int sc = colb ^ ((row & 7) << 4);
    stage16(kg + (size_t)row * 128 + sc, (char*)Ks[0] + off);
    stage16(vg + (size_t)row * 4096 + sc, (char*)Vs[0] + off);
  }
  __syncthreads();

  int cur = 0;
  for (int kt = 0; kt < nkt; ++kt) {
    const int k0 = kt << 6;
    if (kt + 1 < nkt) {
      const int k0n = k0 + 64;
#pragma unroll
      for (int i = 0; i < 2; ++i) {
        const int off = so + i * 4096;
        const int row = off >> 7, colb = off & 127;
        const int sc = colb ^ ((row & 7) << 4);
        stage16(kg + (size_t)(k0n + row) * 128 + sc, (char*)Ks[cur ^ 1] + off);
        stage16(vg + (size_t)row * 4096 + (size_t)(k0n << 1) + sc, (char*)Vs[cur ^ 1] + off);
      }
    }
    if (k0 <= wave_kmax) {
      const int sw = (l31 & 7) << 4;
      // ---- QK^T: sc32[kb] = K-block(kb) . Q ----
      f32x16 s32[2];
      __builtin_amdgcn_s_setprio(1);
#pragma unroll
      for (int kb = 0; kb < 2; ++kb) {
        const char* kr = (const char*)Ks[cur] + (kb * 32 + l31) * 128;
        f32x16 s = vzero16;
#pragma unroll
        for (int ds = 0; ds < 4; ++ds) {
          bf16x8 kf = *(const bf16x8*)(kr + ((ds * 32 + lh * 16) ^ sw));
          s = mfma32(kf, qf[ds], s);
        }
        s32[kb] = s;
      }
      __builtin_amdgcn_s_setprio(0);

      if (lat && (k0 + 63 > q0w)) {   // causal straddle mask
        const int qg = q0w + l31;
#pragma unroll
        for (int kb = 0; kb < 2; ++kb)
#pragma unroll
          for (int r = 0; r < 16; ++r) {
            const int key = k0 + kb * 32 + (r & 3) + 8 * (r >> 2) + 4 * lh;
            if (key > qg) s32[kb][r] = -1e30f;
          }
      }
      // ---- row max (per-lane q) ----
      float tmax = s32[0][0];
#pragma unroll
      for (int kb = 0; kb < 2; ++kb)
#pragma unroll
        for (int r = 0; r < 16; ++r) tmax = fmaxf(tmax, s32[kb][r]);
      tmax = fmaxf(tmax, __shfl_xor(tmax, 32));
      if (__any(tmax > mreg + 8.0f)) {  // defer-max rescale (rare)
        float mnew = fmaxf(mreg, tmax);
        float scale = fexp2(mreg - mnew);
        mreg = mnew;
        lsum *= scale;
        if (lh == 0) ldsL[wid][l31] = scale;
        __builtin_amdgcn_s_waitcnt(0);  // lgkm drain for same-wave LDS RAW
#pragma unroll
        for (int r = 0; r < 16; ++r) {
          const float scq = ldsL[wid][(r & 3) + 8 * (r >> 2) + 4 * lh];
          oacc[0][r] *= scq;
          oacc[1][r] *= scq;
        }
      }
      // ---- P = 2^(S-m), pack, lsum ----
      unsigned w[16];
#pragma unroll
      for (int kb = 0; kb < 2; ++kb) {
        float p[16];
#pragma unroll
        for (int r = 0; r < 16; ++r) {
          p[r] = fexp2(s32[kb][r] - mreg);
          lsum += p[r];
        }
#pragma unroll
        for (int m = 0; m < 8; ++m) w[kb * 8 + m] = pkbf(p[2 * m], p[2 * m + 1]);
      }
      // ---- PV: A(t) built via permlane32_swap; B = V^T from LDS ----
#pragma unroll
      for (int t = 0; t < 4; ++t) {
        const int g = t * 4;
        plswap(w[g], w[g + 2]);
        plswap(w[g + 1], w[g + 3]);
        union { unsigned uw[4]; bf16x8 v; } A;
        A.uw[0] = w[g]; A.uw[1] = w[g + 1]; A.uw[2] = w[g + 2]; A.uw[3] = w[g + 3];
        __builtin_amdgcn_s_setprio(1);
#pragma unroll
        for (int db = 0; db < 2; ++db) {
          const char* vr = (const char*)Vs[cur] + (db * 32 + l31) * 128;
          bf16x8 bv = *(const bf16x8*)(vr + ((t * 32 + lh * 16) ^ sw));
          oacc[db] = mfma32(A.v, bv, oacc[db]);
        }
        __builtin_amdgcn_s_setprio(0);
      }
    }
    __syncthreads();
    cur ^= 1;
  }
  // ---- epilogue ----
  float lt = lsum + __shfl_xor(lsum, 32);
  if (lh == 0) ldsL[wid][l31] = 1.f / lt;
  __builtin_amdgcn_s_waitcnt(0);
  const int orow_base = lat ? (q0w - 1536) : (512 + q0w);
#pragma unroll
  for (int db = 0; db < 2; ++db)
#pragma unroll
    for (int r = 0; r < 16; ++r) {
      const int qv = (r & 3) + 8 * (r >> 2) + 4 * lh;
      out_all[((size_t)b * 2048 + orow_base + qv) * 1024 + h * 64 + db * 32 + l31] =
          f2bf(oacc[db][r] * ldsL[wid][qv]);
    }
}

extern "C" void kernel_launch(void* const* d_in, const int* in_sizes, int n_in,
                              void* d_out, int out_size, void* d_ws, size_t ws_size,
                              hipStream_t stream) {
  const float* x    = (const float*)d_in[0];
  const float* Wq   = (const float*)d_in[1];
  const float* Wkv  = (const float*)d_in[2];
  const float* Wo   = (const float*)d_in[3];
  const float* bo   = (const float*)d_in[4];
  const float* ln_g = (const float*)d_in[5];
  const float* ln_b = (const float*)d_in[6];
  float* out = (float*)d_out;
  char* ws = (char*)d_ws;

  u16* xb      = (u16*)(ws + 0);                      // 8MB (dead after gemm1)
  u16* out_all = (u16*)(ws + 0);                      // 8MB
  u16* wqkv_b  = (u16*)(ws + (size_t)(8u << 20));     // 4MB
  u16* wo_b    = (u16*)(ws + (size_t)(12u << 20));    // 2MB
  u16* qkv_b   = (u16*)(ws + (size_t)(14u << 20));    // 16MB
  u16* q_b     = (u16*)(ws + (size_t)(30u << 20));    // 8MB
  u16* k_b     = (u16*)(ws + (size_t)(38u << 20));    // 8MB
  u16* vT_b    = (u16*)(ws + (size_t)(46u << 20));    // 8MB

  cvt_kernel<<<4096, 256, 0, stream>>>(x, xb, 4194304);
  cvtW_kernel<<<3072, 256, 0, stream>>>(Wq, Wkv, Wo, wqkv_b, wo_b);

  gemm_nt<0><<<dim3(16, 32), 256, 0, stream>>>(xb, wqkv_b, 4096, 2048, 1024,
                                               qkv_b, nullptr, nullptr);
  rope_ln_kernel<<<16384, 256, 0, stream>>>(qkv_b, ln_g, ln_b, q_b, k_b, vT_b);
  attn_kernel<<<512, 256, 0, stream>>>(q_b, k_b, vT_b, out_all);
  gemm_nt<1><<<dim3(8, 32), 256, 0, stream>>>(out_all, wo_b, 4096, 1024, 1024,
                                              nullptr, out, bo);
}